// Round 16
// baseline (874.101 us; speedup 1.0000x reference)
//
#include <hip/hip_runtime.h>

#define HH 448
#define WW 512
#define NPIX (HH * WW)

struct Res { int idx; float ent; };

__device__ __forceinline__ float lrelu(float v) { return v > 0.0f ? v : 0.01f * v; }

__device__ __forceinline__ Res argmax_ent16(const float* __restrict__ v) {
    float m = v[0]; int idx = 0;
#pragma unroll
    for (int i = 1; i < 16; i++) { if (v[i] > m) { m = v[i]; idx = i; } }
    float s = 0.0f, dot = 0.0f;
#pragma unroll
    for (int i = 0; i < 16; i++) {
        float t = __expf(v[i] - m);
        s += t;
        dot = fmaf(t, v[i], dot);
    }
    Res r; r.idx = idx; r.ent = m + __logf(s) - dot / s;
    return r;
}

// Neuron-parallel expert MLP 32->32->32->16 for ONE same-expert pixel pair per wave.
// lane = half*32 + o: computes neuron o of pixel_{half}. Weights are wave-uniform
// (same expert e for all 64 lanes) and consecutive in o -> coalesced, replay-free.
// Per-neuron accumulation order (i ascending) matches the reference bitwise.
__device__ __forceinline__ Res neuron_mlp(
    const float* __restrict__ xb, int p, int sbase, int o,
    const float* __restrict__ w0, const float* __restrict__ b0,
    const float* __restrict__ w1, const float* __restrict__ b1,
    const float* __restrict__ w2, const float* __restrict__ b2,
    size_t e) {
    const float* W0 = w0 + e * 1024;
    const float* W1 = w1 + e * 1024;
    const float* W2 = w2 + e * 512;
    float xr = xb[(size_t)o * NPIX + p];   // channel o of this half's pixel
    float acc = b0[e * 32 + o];
#pragma unroll
    for (int i = 0; i < 32; i++)
        acc = fmaf(W0[i * 32 + o], __shfl(xr, sbase + i, 64), acc);
    float xr2 = lrelu(acc);                // lane o now holds y_o -> next layer's shfl source
    float acc2 = b1[e * 32 + o];
#pragma unroll
    for (int i = 0; i < 32; i++)
        acc2 = fmaf(W1[i * 32 + o], __shfl(xr2, sbase + i, 64), acc2);
    float xr3 = lrelu(acc2);
    int o16 = o & 15;                      // lanes o>=16 duplicate neuron o-16 (ignored)
    float acc3 = b2[e * 16 + o16];
#pragma unroll
    for (int i = 0; i < 32; i++)
        acc3 = fmaf(W2[i * 16 + o16], __shfl(xr3, sbase + i, 64), acc3);
    float z[16];
#pragma unroll
    for (int k = 0; k < 16; k++) z[k] = __shfl(acc3, sbase + k, 64);
    return argmax_ent16(z);                // computed uniformly; owner lane stores
}

// NPX pixels, weight layout [OUT][in=32] (stage 1, per-line uniform weights).
template <int NPX, int OUT>
__device__ __forceinline__ void layer_oiN(const float* __restrict__ w,
                                          const float* __restrict__ b,
                                          const float* __restrict__ x,
                                          float* __restrict__ y) {
#pragma unroll
    for (int o = 0; o < OUT; o++) {
        const float4* row = (const float4*)(w + o * 32);
        float a[NPX];
#pragma unroll
        for (int n = 0; n < NPX; n++) a[n] = b[o];
#pragma unroll
        for (int q = 0; q < 8; q++) {
            float4 wv = row[q];
#pragma unroll
            for (int n = 0; n < NPX; n++) {
                a[n] = fmaf(wv.x, x[n * 32 + 4 * q + 0], a[n]);
                a[n] = fmaf(wv.y, x[n * 32 + 4 * q + 1], a[n]);
                a[n] = fmaf(wv.z, x[n * 32 + 4 * q + 2], a[n]);
                a[n] = fmaf(wv.w, x[n * 32 + 4 * q + 3], a[n]);
            }
        }
#pragma unroll
        for (int n = 0; n < NPX; n++) y[n * 32 + o] = a[n];
    }
}

__global__ __launch_bounds__(128, 2) void cls3_kernel(
    const float* __restrict__ x_in,
    const float* __restrict__ w1_0, const float* __restrict__ b1_0,
    const float* __restrict__ w1_1, const float* __restrict__ b1_1,
    const float* __restrict__ w1_2, const float* __restrict__ b1_2,
    const float* __restrict__ w2_0, const float* __restrict__ b2_0,
    const float* __restrict__ w2_1, const float* __restrict__ b2_1,
    const float* __restrict__ w2_2, const float* __restrict__ b2_2,
    const float* __restrict__ w3_0, const float* __restrict__ b3_0,
    const float* __restrict__ w3_1, const float* __restrict__ b3_1,
    const float* __restrict__ w3_2, const float* __restrict__ b3_2,
    float* __restrict__ out) {
    __shared__ int sCls[256];
    __shared__ int sRaw[256];
    __shared__ int sPerm[512];   // even-aligned slots (<=448 used)
    __shared__ int sCnt[192];
    __shared__ int sScan[192];
    __shared__ int sOffs[192];
    __shared__ int sTot;

    // XCD-pair swizzle: both half-line blocks of line h land on the same XCD.
    const int bid = blockIdx.x;
    const int xcd = bid & 7;
    const int idx = bid >> 3;            // 0..111
    const int h = xcd * 56 + (idx >> 1); // 0..447
    const int base = (idx & 1) << 8;     // 0 or 256 within the line
    const int t = threadIdx.x;           // 0..127
    const size_t rowoff = (size_t)h * WW + base;

    const int wv = t >> 6;               // wave id 0/1
    const int lane = t & 63;
    const int half = lane >> 5;          // which pixel of the pair
    const int sbase = half << 5;
    const int o = lane & 31;             // neuron index

    // ---- stage 1: 2 px/thread (t, t+128), per-line uniform weights ----
    {
        float x[64], y[64];
#pragma unroll
        for (int c = 0; c < 32; c++) {
            x[c]      = x_in[(size_t)c * NPIX + rowoff + t];
            x[32 + c] = x_in[(size_t)c * NPIX + rowoff + t + 128];
        }
        layer_oiN<2, 32>(w1_0 + (size_t)h * 1024, b1_0 + (size_t)h * 32, x, y);
#pragma unroll
        for (int k = 0; k < 64; k++) y[k] = lrelu(y[k]);
        layer_oiN<2, 32>(w1_1 + (size_t)h * 1024, b1_1 + (size_t)h * 32, y, x);
#pragma unroll
        for (int k = 0; k < 64; k++) x[k] = lrelu(x[k]);
        layer_oiN<2, 16>(w1_2 + (size_t)h * 512, b1_2 + (size_t)h * 16, x, y);
        Res r0 = argmax_ent16(y);
        Res r1 = argmax_ent16(y + 32);
        out[NPIX + rowoff + t] = r0.ent;          // e1
        out[NPIX + rowoff + t + 128] = r1.ent;
        sCls[t] = r0.idx;
        sCls[t + 128] = r1.idx;
    }
    if (t < 16) sCnt[t] = 0;
    __syncthreads();

    // ---- counting sort by inds1 (16 bins, even-aligned segments) ----
    int rkA = atomicAdd(&sCnt[sCls[t]], 1);
    int rkB = atomicAdd(&sCnt[sCls[t + 128]], 1);
    __syncthreads();
    if (t < 16) {
        int ce = (sCnt[t] + 1) & ~1;
        int incl = ce;
#pragma unroll
        for (int d = 1; d < 16; d <<= 1) {
            int n = __shfl_up(incl, d, 64);
            if (t >= d) incl += n;
        }
        sOffs[t] = incl - ce;
        if (t == 15) sTot = incl;
    }
    __syncthreads();
    sPerm[sOffs[sCls[t]] + rkA] = t;
    sPerm[sOffs[sCls[t + 128]] + rkB] = t + 128;
    __syncthreads();
    if (t < 16 && (sCnt[t] & 1)) {   // duplicate last pixel of odd segments
        int g = sOffs[t] + sCnt[t];
        sPerm[g] = sPerm[g - 1];
    }
    __syncthreads();

    // ---- stage 2: one same-expert pair per wave, neuron-parallel ----
    {
        const int P = sTot >> 1;
        const float* xb = x_in + (size_t)32 * NPIX + rowoff;
        for (int g = wv; g < P; g += 2) {
            int p = sPerm[2 * g + half];
            int c1 = sCls[p];
            size_t e = (size_t)h * 16 + c1;
            Res r = neuron_mlp(xb, p, sbase, o,
                               w2_0, b2_0, w2_1, b2_1, w2_2, b2_2, e);
            if (o == 0) {
                out[2 * NPIX + rowoff + p] = r.ent;   // e2
                int raw = c1 * 12 + r.idx - 2;
                sRaw[p] = raw;
                int cl = raw < 0 ? 0 : (raw > 191 ? 191 : raw);
                sCls[p] = cl;   // own pair's pixel (dup pair: identical double write)
            }
        }
    }
    __syncthreads();
    sCnt[t] = 0;
    if (t < 64) sCnt[128 + t] = 0;
    __syncthreads();

    // ---- counting sort by clipped inds12 (192 bins, even-aligned segments) ----
    rkA = atomicAdd(&sCnt[sCls[t]], 1);
    rkB = atomicAdd(&sCnt[sCls[t + 128]], 1);
    __syncthreads();
    {
        int lane2 = t & 63;
        if (t < 64) {
            int ce = (sCnt[lane2] + 1) & ~1;
            int incl = ce;
#pragma unroll
            for (int d = 1; d < 64; d <<= 1) {
                int n = __shfl_up(incl, d, 64);
                if (lane2 >= d) incl += n;
            }
            sScan[lane2] = incl;
            int ce2 = (sCnt[128 + lane2] + 1) & ~1;
            int incl2 = ce2;
#pragma unroll
            for (int d = 1; d < 64; d <<= 1) {
                int n = __shfl_up(incl2, d, 64);
                if (lane2 >= d) incl2 += n;
            }
            sScan[128 + lane2] = incl2;
        } else {
            int ce = (sCnt[64 + lane2] + 1) & ~1;
            int incl = ce;
#pragma unroll
            for (int d = 1; d < 64; d <<= 1) {
                int n = __shfl_up(incl, d, 64);
                if (lane2 >= d) incl += n;
            }
            sScan[64 + lane2] = incl;
        }
    }
    __syncthreads();
    {
        int ce = (sCnt[t] + 1) & ~1;
        sOffs[t] = sScan[t] - ce + (t >= 64 ? sScan[63] : 0);
        if (t < 64) {
            int b2i = 128 + t;
            int ce2 = (sCnt[b2i] + 1) & ~1;
            sOffs[b2i] = sScan[b2i] - ce2 + sScan[63] + sScan[127];
        }
        if (t == 0) sTot = sScan[63] + sScan[127] + sScan[191];
    }
    __syncthreads();
    sPerm[sOffs[sCls[t]] + rkA] = t;
    sPerm[sOffs[sCls[t + 128]] + rkB] = t + 128;
    __syncthreads();
    {
        if (sCnt[t] & 1) { int g = sOffs[t] + sCnt[t]; sPerm[g] = sPerm[g - 1]; }
        if (t < 64) {
            int b2i = 128 + t;
            if (sCnt[b2i] & 1) { int g = sOffs[b2i] + sCnt[b2i]; sPerm[g] = sPerm[g - 1]; }
        }
    }
    __syncthreads();

    // ---- stage 3: one same-expert pair per wave, neuron-parallel ----
    {
        const int P = sTot >> 1;
        const float* xb = x_in + (size_t)64 * NPIX + rowoff;
        for (int g = wv; g < P; g += 2) {
            int p = sPerm[2 * g + half];
            int cl = sCls[p];
            size_t e = (size_t)h * 192 + cl;
            Res r = neuron_mlp(xb, p, sbase, o,
                               w3_0, b3_0, w3_1, b3_1, w3_2, b3_2, e);
            if (o == 0) {
                int raw = sRaw[p];
                out[3 * NPIX + rowoff + p] = r.ent;   // e3
                int i123 = raw * 8 + r.idx - 4;
                i123 = i123 < 0 ? 0 : (i123 > 1535 ? 1535 : i123);
                out[rowoff + p] = (float)i123;        // inds123 as float
            }
        }
    }
}

extern "C" void kernel_launch(void* const* d_in, const int* in_sizes, int n_in,
                              void* d_out, int out_size, void* d_ws, size_t ws_size,
                              hipStream_t stream) {
    const float* P[19];
    for (int i = 0; i < 19 && i < n_in; i++) P[i] = (const float*)d_in[i];

    const float *x_in, *W1[3], *B1[3], *W2[3], *B2[3], *W3[3], *B3[3];
    x_in = P[0];
    bool dict_order = (in_sizes[2] == 448 * 32);
    if (dict_order) {
        W1[0] = P[1];  B1[0] = P[2];  W1[1] = P[3];  B1[1] = P[4];  W1[2] = P[5];  B1[2] = P[6];
        W2[0] = P[7];  B2[0] = P[8];  W2[1] = P[9];  B2[1] = P[10]; W2[2] = P[11]; B2[2] = P[12];
        W3[0] = P[13]; B3[0] = P[14]; W3[1] = P[15]; B3[1] = P[16]; W3[2] = P[17]; B3[2] = P[18];
    } else {
        W1[0] = P[1];  W1[1] = P[2];  W1[2] = P[3];  B1[0] = P[4];  B1[1] = P[5];  B1[2] = P[6];
        W2[0] = P[7];  W2[1] = P[8];  W2[2] = P[9];  B2[0] = P[10]; B2[1] = P[11]; B2[2] = P[12];
        W3[0] = P[13]; W3[1] = P[14]; W3[2] = P[15]; B3[0] = P[16]; B3[1] = P[17]; B3[2] = P[18];
    }

    float* out = (float*)d_out;
    hipLaunchKernelGGL(cls3_kernel, dim3(2 * HH), dim3(128), 0, stream,
                       x_in,
                       W1[0], B1[0], W1[1], B1[1], W1[2], B1[2],
                       W2[0], B2[0], W2[1], B2[1], W2[2], B2[2],
                       W3[0], B3[0], W3[1], B3[1], W3[2], B3[2],
                       out);
}

// Round 17
// 213.206 us; speedup vs baseline: 4.0998x; 4.0998x over previous
//
#include <hip/hip_runtime.h>

#define HH 448
#define WW 512
#define NPIX (HH * WW)

struct Res { int idx; float ent; };

__device__ __forceinline__ float lrelu(float v) { return v > 0.0f ? v : 0.01f * v; }

__device__ __forceinline__ Res argmax_ent16(const float* __restrict__ v) {
    float m = v[0]; int idx = 0;
#pragma unroll
    for (int i = 1; i < 16; i++) { if (v[i] > m) { m = v[i]; idx = i; } }
    float s = 0.0f, dot = 0.0f;
#pragma unroll
    for (int i = 0; i < 16; i++) {
        float t = __expf(v[i] - m);
        s += t;
        dot = fmaf(t, v[i], dot);
    }
    Res r; r.idx = idx; r.ent = m + __logf(s) - dot / s;
    return r;
}

// NPX pixels, weight layout [in=32][OUT] (stages 2/3). Per-pixel fma order identical
// to the 1-pixel version (bitwise-stable). One weight float4 feeds 4*NPX fmas.
template <int NPX, int OUT>
__device__ __forceinline__ void layer_ioN(const float* __restrict__ w,
                                          const float* __restrict__ b,
                                          const float* __restrict__ x,
                                          float* __restrict__ y) {
    float acc[NPX][OUT];
#pragma unroll
    for (int n = 0; n < NPX; n++)
#pragma unroll
        for (int o = 0; o < OUT; o++) acc[n][o] = b[o];
#pragma unroll
    for (int i = 0; i < 32; i++) {
        const float4* row = (const float4*)(w + i * OUT);
#pragma unroll
        for (int q = 0; q < OUT / 4; q++) {
            float4 wv = row[q];
#pragma unroll
            for (int n = 0; n < NPX; n++) {
                float xi = x[n * 32 + i];
                acc[n][4 * q + 0] = fmaf(xi, wv.x, acc[n][4 * q + 0]);
                acc[n][4 * q + 1] = fmaf(xi, wv.y, acc[n][4 * q + 1]);
                acc[n][4 * q + 2] = fmaf(xi, wv.z, acc[n][4 * q + 2]);
                acc[n][4 * q + 3] = fmaf(xi, wv.w, acc[n][4 * q + 3]);
            }
        }
    }
#pragma unroll
    for (int n = 0; n < NPX; n++)
#pragma unroll
        for (int o = 0; o < OUT; o++) y[n * 32 + o] = acc[n][o];
}

// NPX pixels, weight layout [OUT][in=32] (stage 1, per-line uniform weights).
template <int NPX, int OUT>
__device__ __forceinline__ void layer_oiN(const float* __restrict__ w,
                                          const float* __restrict__ b,
                                          const float* __restrict__ x,
                                          float* __restrict__ y) {
#pragma unroll
    for (int o = 0; o < OUT; o++) {
        const float4* row = (const float4*)(w + o * 32);
        float a[NPX];
#pragma unroll
        for (int n = 0; n < NPX; n++) a[n] = b[o];
#pragma unroll
        for (int q = 0; q < 8; q++) {
            float4 wv = row[q];
#pragma unroll
            for (int n = 0; n < NPX; n++) {
                a[n] = fmaf(wv.x, x[n * 32 + 4 * q + 0], a[n]);
                a[n] = fmaf(wv.y, x[n * 32 + 4 * q + 1], a[n]);
                a[n] = fmaf(wv.z, x[n * 32 + 4 * q + 2], a[n]);
                a[n] = fmaf(wv.w, x[n * 32 + 4 * q + 3], a[n]);
            }
        }
#pragma unroll
        for (int n = 0; n < NPX; n++) y[n * 32 + o] = a[n];
    }
}

// 2-pixel expert MLP 32->32->32->16, shared expert e (per-lane global weights).
__device__ __forceinline__ void expert_mlp2(const float* __restrict__ xb,
                                            const int* __restrict__ p,
                                            const float* __restrict__ w0, const float* __restrict__ b0,
                                            const float* __restrict__ w1, const float* __restrict__ b1,
                                            const float* __restrict__ w2, const float* __restrict__ b2,
                                            size_t e, Res* __restrict__ r) {
    float x[64], y[64];
#pragma unroll
    for (int n = 0; n < 2; n++)
#pragma unroll
        for (int c = 0; c < 32; c++) x[n * 32 + c] = xb[(size_t)c * NPIX + p[n]];
    layer_ioN<2, 32>(w0 + e * 1024, b0 + e * 32, x, y);
#pragma unroll
    for (int k = 0; k < 64; k++) y[k] = lrelu(y[k]);
    layer_ioN<2, 32>(w1 + e * 1024, b1 + e * 32, y, x);
#pragma unroll
    for (int k = 0; k < 64; k++) x[k] = lrelu(x[k]);
    layer_ioN<2, 16>(w2 + e * 512, b2 + e * 16, x, y);
    r[0] = argmax_ent16(y);
    r[1] = argmax_ent16(y + 32);
}

__global__ __launch_bounds__(64, 2) void cls3_kernel(
    const float* __restrict__ x_in,
    const float* __restrict__ w1_0, const float* __restrict__ b1_0,
    const float* __restrict__ w1_1, const float* __restrict__ b1_1,
    const float* __restrict__ w1_2, const float* __restrict__ b1_2,
    const float* __restrict__ w2_0, const float* __restrict__ b2_0,
    const float* __restrict__ w2_1, const float* __restrict__ b2_1,
    const float* __restrict__ w2_2, const float* __restrict__ b2_2,
    const float* __restrict__ w3_0, const float* __restrict__ b3_0,
    const float* __restrict__ w3_1, const float* __restrict__ b3_1,
    const float* __restrict__ w3_2, const float* __restrict__ b3_2,
    float* __restrict__ out) {
    __shared__ int sCls[128];
    __shared__ int sRaw[128];
    __shared__ int sPerm[256];   // even-aligned slots (<=256 used)
    __shared__ int sCnt[192];
    __shared__ int sScan[192];
    __shared__ int sOffs[192];
    __shared__ int sTot;

    // XCD swizzle: all 4 quarter-line blocks of line h land on the same XCD.
    const int bid = blockIdx.x;          // 0..1791
    const int xcd = bid & 7;
    const int idx = bid >> 3;            // 0..223
    const int h = xcd * 56 + (idx >> 2); // 56 lines per XCD
    const int base = (idx & 3) << 7;     // 0,128,256,384 within the line
    const int t = threadIdx.x;           // 0..63 (single wave)
    const size_t rowoff = (size_t)h * WW + base;

    // ---- stage 1: 2 px/thread (t, t+64), per-line uniform weights ----
    {
        float x[64], y[64];
#pragma unroll
        for (int c = 0; c < 32; c++) {
            x[c]      = x_in[(size_t)c * NPIX + rowoff + t];
            x[32 + c] = x_in[(size_t)c * NPIX + rowoff + t + 64];
        }
        layer_oiN<2, 32>(w1_0 + (size_t)h * 1024, b1_0 + (size_t)h * 32, x, y);
#pragma unroll
        for (int k = 0; k < 64; k++) y[k] = lrelu(y[k]);
        layer_oiN<2, 32>(w1_1 + (size_t)h * 1024, b1_1 + (size_t)h * 32, y, x);
#pragma unroll
        for (int k = 0; k < 64; k++) x[k] = lrelu(x[k]);
        layer_oiN<2, 16>(w1_2 + (size_t)h * 512, b1_2 + (size_t)h * 16, x, y);
        Res r0 = argmax_ent16(y);
        Res r1 = argmax_ent16(y + 32);
        out[NPIX + rowoff + t] = r0.ent;          // e1
        out[NPIX + rowoff + t + 64] = r1.ent;
        sCls[t] = r0.idx;
        sCls[t + 64] = r1.idx;
    }
    if (t < 16) sCnt[t] = 0;
    __syncthreads();

    // ---- counting sort by inds1 (16 bins, 128 px, even-aligned segments) ----
    int rkA = atomicAdd(&sCnt[sCls[t]], 1);
    int rkB = atomicAdd(&sCnt[sCls[t + 64]], 1);
    __syncthreads();
    if (t < 16) {
        int ce = (sCnt[t] + 1) & ~1;
        int incl = ce;
#pragma unroll
        for (int d = 1; d < 16; d <<= 1) {
            int n = __shfl_up(incl, d, 64);
            if (t >= d) incl += n;
        }
        sOffs[t] = incl - ce;
        if (t == 15) sTot = incl;
    }
    __syncthreads();
    sPerm[sOffs[sCls[t]] + rkA] = t;
    sPerm[sOffs[sCls[t + 64]] + rkB] = t + 64;
    __syncthreads();
    if (t < 16 && (sCnt[t] & 1)) {   // duplicate last pixel of odd segments
        int g = sOffs[t] + sCnt[t];
        sPerm[g] = sPerm[g - 1];
    }
    __syncthreads();

    // ---- stage 2: same-expert pairs (one pair per lane) ----
    {
        const int P = sTot >> 1;
        const float* xb = x_in + (size_t)32 * NPIX + rowoff;
        for (int j = t; j < P; j += 64) {
            int pp[2] = { sPerm[2 * j], sPerm[2 * j + 1] };
            int c1 = sCls[pp[0]];
            Res rr[2];
            expert_mlp2(xb, pp, w2_0, b2_0, w2_1, b2_1, w2_2, b2_2,
                        (size_t)h * 16 + c1, rr);
#pragma unroll
            for (int n = 0; n < 2; n++) {
                int q = pp[n];
                out[2 * NPIX + rowoff + q] = rr[n].ent;   // e2
                int raw = c1 * 12 + rr[n].idx - 2;
                sRaw[q] = raw;
                int cl = raw < 0 ? 0 : (raw > 191 ? 191 : raw);
                sCls[q] = cl;   // own pair's pixels only (dup writes same value)
            }
        }
    }
    __syncthreads();
    sCnt[t] = 0; sCnt[64 + t] = 0; sCnt[128 + t] = 0;
    __syncthreads();

    // ---- counting sort by clipped inds12 (192 bins, 128 px, even-aligned) ----
    rkA = atomicAdd(&sCnt[sCls[t]], 1);
    rkB = atomicAdd(&sCnt[sCls[t + 64]], 1);
    __syncthreads();
    {
        // 3 chunk-local scans with a single 64-lane wave
#pragma unroll
        for (int c = 0; c < 3; c++) {
            int ce = (sCnt[c * 64 + t] + 1) & ~1;
            int incl = ce;
#pragma unroll
            for (int d = 1; d < 64; d <<= 1) {
                int n = __shfl_up(incl, d, 64);
                if (t >= d) incl += n;
            }
            sScan[c * 64 + t] = incl;
        }
    }
    __syncthreads();
    {
        int ce0 = (sCnt[t] + 1) & ~1;
        sOffs[t] = sScan[t] - ce0;
        int b1i = 64 + t;
        int ce1 = (sCnt[b1i] + 1) & ~1;
        sOffs[b1i] = sScan[b1i] - ce1 + sScan[63];
        int b2i = 128 + t;
        int ce2 = (sCnt[b2i] + 1) & ~1;
        sOffs[b2i] = sScan[b2i] - ce2 + sScan[63] + sScan[127];
        if (t == 0) sTot = sScan[63] + sScan[127] + sScan[191];
    }
    __syncthreads();
    sPerm[sOffs[sCls[t]] + rkA] = t;
    sPerm[sOffs[sCls[t + 64]] + rkB] = t + 64;
    __syncthreads();
    {
        if (sCnt[t] & 1)       { int g = sOffs[t] + sCnt[t];             sPerm[g] = sPerm[g - 1]; }
        if (sCnt[64 + t] & 1)  { int g = sOffs[64 + t] + sCnt[64 + t];   sPerm[g] = sPerm[g - 1]; }
        if (sCnt[128 + t] & 1) { int g = sOffs[128 + t] + sCnt[128 + t]; sPerm[g] = sPerm[g - 1]; }
    }
    __syncthreads();

    // ---- stage 3: same-expert pairs ----
    {
        const int P = sTot >> 1;
        const float* xb = x_in + (size_t)64 * NPIX + rowoff;
        for (int j = t; j < P; j += 64) {
            int pp[2] = { sPerm[2 * j], sPerm[2 * j + 1] };
            int cl = sCls[pp[0]];
            Res rr[2];
            expert_mlp2(xb, pp, w3_0, b3_0, w3_1, b3_1, w3_2, b3_2,
                        (size_t)h * 192 + cl, rr);
#pragma unroll
            for (int n = 0; n < 2; n++) {
                int q = pp[n];
                int raw = sRaw[q];
                out[3 * NPIX + rowoff + q] = rr[n].ent;   // e3
                int i123 = raw * 8 + rr[n].idx - 4;
                i123 = i123 < 0 ? 0 : (i123 > 1535 ? 1535 : i123);
                out[rowoff + q] = (float)i123;            // inds123 as float
            }
        }
    }
}

extern "C" void kernel_launch(void* const* d_in, const int* in_sizes, int n_in,
                              void* d_out, int out_size, void* d_ws, size_t ws_size,
                              hipStream_t stream) {
    const float* P[19];
    for (int i = 0; i < 19 && i < n_in; i++) P[i] = (const float*)d_in[i];

    const float *x_in, *W1[3], *B1[3], *W2[3], *B2[3], *W3[3], *B3[3];
    x_in = P[0];
    bool dict_order = (in_sizes[2] == 448 * 32);
    if (dict_order) {
        W1[0] = P[1];  B1[0] = P[2];  W1[1] = P[3];  B1[1] = P[4];  W1[2] = P[5];  B1[2] = P[6];
        W2[0] = P[7];  B2[0] = P[8];  W2[1] = P[9];  B2[1] = P[10]; W2[2] = P[11]; B2[2] = P[12];
        W3[0] = P[13]; B3[0] = P[14]; W3[1] = P[15]; B3[1] = P[16]; W3[2] = P[17]; B3[2] = P[18];
    } else {
        W1[0] = P[1];  W1[1] = P[2];  W1[2] = P[3];  B1[0] = P[4];  B1[1] = P[5];  B1[2] = P[6];
        W2[0] = P[7];  W2[1] = P[8];  W2[2] = P[9];  B2[0] = P[10]; B2[1] = P[11]; B2[2] = P[12];
        W3[0] = P[13]; W3[1] = P[14]; W3[2] = P[15]; B3[0] = P[16]; B3[1] = P[17]; B3[2] = P[18];
    }

    float* out = (float*)d_out;
    hipLaunchKernelGGL(cls3_kernel, dim3(4 * HH), dim3(64), 0, stream,
                       x_in,
                       W1[0], B1[0], W1[1], B1[1], W1[2], B1[2],
                       W2[0], B2[0], W2[1], B2[1], W2[2], B2[2],
                       W3[0], B3[0], W3[1], B3[1], W3[2], B3[2],
                       out);
}

// Round 18
// 197.597 us; speedup vs baseline: 4.4237x; 1.0790x over previous
//
#include <hip/hip_runtime.h>

#define HH 448
#define WW 512
#define NPIX (HH * WW)

struct Res { int idx; float ent; };

__device__ __forceinline__ float lrelu(float v) { return v > 0.0f ? v : 0.01f * v; }

__device__ __forceinline__ Res argmax_ent16(const float* __restrict__ v) {
    float m = v[0]; int idx = 0;
#pragma unroll
    for (int i = 1; i < 16; i++) { if (v[i] > m) { m = v[i]; idx = i; } }
    float s = 0.0f, dot = 0.0f;
#pragma unroll
    for (int i = 0; i < 16; i++) {
        float t = __expf(v[i] - m);
        s += t;
        dot = fmaf(t, v[i], dot);
    }
    Res r; r.idx = idx; r.ent = m + __logf(s) - dot / s;
    return r;
}

// NPX pixels, weight layout [in=32][OUT] (stages 2/3). Per-pixel fma order identical
// to the 1-pixel version (bitwise-stable). One weight float4 feeds 4*NPX fmas.
template <int NPX, int OUT>
__device__ __forceinline__ void layer_ioN(const float* __restrict__ w,
                                          const float* __restrict__ b,
                                          const float* __restrict__ x,
                                          float* __restrict__ y) {
    float acc[NPX][OUT];
#pragma unroll
    for (int n = 0; n < NPX; n++)
#pragma unroll
        for (int o = 0; o < OUT; o++) acc[n][o] = b[o];
#pragma unroll
    for (int i = 0; i < 32; i++) {
        const float4* row = (const float4*)(w + i * OUT);
#pragma unroll
        for (int q = 0; q < OUT / 4; q++) {
            float4 wv = row[q];
#pragma unroll
            for (int n = 0; n < NPX; n++) {
                float xi = x[n * 32 + i];
                acc[n][4 * q + 0] = fmaf(xi, wv.x, acc[n][4 * q + 0]);
                acc[n][4 * q + 1] = fmaf(xi, wv.y, acc[n][4 * q + 1]);
                acc[n][4 * q + 2] = fmaf(xi, wv.z, acc[n][4 * q + 2]);
                acc[n][4 * q + 3] = fmaf(xi, wv.w, acc[n][4 * q + 3]);
            }
        }
    }
#pragma unroll
    for (int n = 0; n < NPX; n++)
#pragma unroll
        for (int o = 0; o < OUT; o++) y[n * 32 + o] = acc[n][o];
}

// NPX pixels, weight layout [OUT][in=32] (stage 1, per-line uniform weights).
template <int NPX, int OUT>
__device__ __forceinline__ void layer_oiN(const float* __restrict__ w,
                                          const float* __restrict__ b,
                                          const float* __restrict__ x,
                                          float* __restrict__ y) {
#pragma unroll
    for (int o = 0; o < OUT; o++) {
        const float4* row = (const float4*)(w + o * 32);
        float a[NPX];
#pragma unroll
        for (int n = 0; n < NPX; n++) a[n] = b[o];
#pragma unroll
        for (int q = 0; q < 8; q++) {
            float4 wv = row[q];
#pragma unroll
            for (int n = 0; n < NPX; n++) {
                a[n] = fmaf(wv.x, x[n * 32 + 4 * q + 0], a[n]);
                a[n] = fmaf(wv.y, x[n * 32 + 4 * q + 1], a[n]);
                a[n] = fmaf(wv.z, x[n * 32 + 4 * q + 2], a[n]);
                a[n] = fmaf(wv.w, x[n * 32 + 4 * q + 3], a[n]);
            }
        }
#pragma unroll
        for (int n = 0; n < NPX; n++) y[n * 32 + o] = a[n];
    }
}

// 2-pixel expert MLP 32->32->32->16, shared expert e (per-lane global weights).
__device__ __forceinline__ void expert_mlp2(const float* __restrict__ xb,
                                            const int* __restrict__ p,
                                            const float* __restrict__ w0, const float* __restrict__ b0,
                                            const float* __restrict__ w1, const float* __restrict__ b1,
                                            const float* __restrict__ w2, const float* __restrict__ b2,
                                            size_t e, Res* __restrict__ r) {
    float x[64], y[64];
#pragma unroll
    for (int n = 0; n < 2; n++)
#pragma unroll
        for (int c = 0; c < 32; c++) x[n * 32 + c] = xb[(size_t)c * NPIX + p[n]];
    layer_ioN<2, 32>(w0 + e * 1024, b0 + e * 32, x, y);
#pragma unroll
    for (int k = 0; k < 64; k++) y[k] = lrelu(y[k]);
    layer_ioN<2, 32>(w1 + e * 1024, b1 + e * 32, y, x);
#pragma unroll
    for (int k = 0; k < 64; k++) x[k] = lrelu(x[k]);
    layer_ioN<2, 16>(w2 + e * 512, b2 + e * 16, x, y);
    r[0] = argmax_ent16(y);
    r[1] = argmax_ent16(y + 32);
}

__global__ __launch_bounds__(128, 2) void cls3_kernel(
    const float* __restrict__ x_in,
    const float* __restrict__ w1_0, const float* __restrict__ b1_0,
    const float* __restrict__ w1_1, const float* __restrict__ b1_1,
    const float* __restrict__ w1_2, const float* __restrict__ b1_2,
    const float* __restrict__ w2_0, const float* __restrict__ b2_0,
    const float* __restrict__ w2_1, const float* __restrict__ b2_1,
    const float* __restrict__ w2_2, const float* __restrict__ b2_2,
    const float* __restrict__ w3_0, const float* __restrict__ b3_0,
    const float* __restrict__ w3_1, const float* __restrict__ b3_1,
    const float* __restrict__ w3_2, const float* __restrict__ b3_2,
    float* __restrict__ out) {
    __shared__ int sCls[256];
    __shared__ int sRaw[256];
    __shared__ int sPerm[512];   // even-aligned slots (<=448 used)
    __shared__ int sCnt[192];
    __shared__ int sScan[192];
    __shared__ int sOffs[192];
    __shared__ int sTot;

    // XCD-pair swizzle: both half-line blocks of line h land on the same XCD
    // (blockIdx round-robins across 8 XCDs; 896 = 8 * 112, 56 lines per XCD).
    const int bid = blockIdx.x;
    const int xcd = bid & 7;
    const int idx = bid >> 3;            // 0..111
    const int h = xcd * 56 + (idx >> 1); // 0..447
    const int base = (idx & 1) << 8;     // 0 or 256 within the line
    const int t = threadIdx.x;           // 0..127
    const size_t rowoff = (size_t)h * WW + base;

    // ---- stage 1: 2 px/thread (t, t+128), per-line uniform weights ----
    {
        float x[64], y[64];
#pragma unroll
        for (int c = 0; c < 32; c++) {
            x[c]      = x_in[(size_t)c * NPIX + rowoff + t];
            x[32 + c] = x_in[(size_t)c * NPIX + rowoff + t + 128];
        }
        layer_oiN<2, 32>(w1_0 + (size_t)h * 1024, b1_0 + (size_t)h * 32, x, y);
#pragma unroll
        for (int k = 0; k < 64; k++) y[k] = lrelu(y[k]);
        layer_oiN<2, 32>(w1_1 + (size_t)h * 1024, b1_1 + (size_t)h * 32, y, x);
#pragma unroll
        for (int k = 0; k < 64; k++) x[k] = lrelu(x[k]);
        layer_oiN<2, 16>(w1_2 + (size_t)h * 512, b1_2 + (size_t)h * 16, x, y);
        Res r0 = argmax_ent16(y);
        Res r1 = argmax_ent16(y + 32);
        out[NPIX + rowoff + t] = r0.ent;          // e1
        out[NPIX + rowoff + t + 128] = r1.ent;
        sCls[t] = r0.idx;
        sCls[t + 128] = r1.idx;
    }
    if (t < 16) sCnt[t] = 0;
    __syncthreads();

    // ---- counting sort by inds1 (16 bins, even-aligned segments) ----
    int rkA = atomicAdd(&sCnt[sCls[t]], 1);
    int rkB = atomicAdd(&sCnt[sCls[t + 128]], 1);
    __syncthreads();
    if (t < 16) {
        int ce = (sCnt[t] + 1) & ~1;
        int incl = ce;
#pragma unroll
        for (int d = 1; d < 16; d <<= 1) {
            int n = __shfl_up(incl, d, 64);
            if (t >= d) incl += n;
        }
        sOffs[t] = incl - ce;
        if (t == 15) sTot = incl;
    }
    __syncthreads();
    sPerm[sOffs[sCls[t]] + rkA] = t;
    sPerm[sOffs[sCls[t + 128]] + rkB] = t + 128;
    __syncthreads();
    if (t < 16 && (sCnt[t] & 1)) {   // duplicate last pixel of odd segments
        int g = sOffs[t] + sCnt[t];
        sPerm[g] = sPerm[g - 1];
    }
    __syncthreads();

    // ---- stage 2: same-expert pairs ----
    {
        const int P = sTot >> 1;
        const float* xb = x_in + (size_t)32 * NPIX + rowoff;
        for (int j = t; j < P; j += 128) {
            int pp[2] = { sPerm[2 * j], sPerm[2 * j + 1] };
            int c1 = sCls[pp[0]];
            Res rr[2];
            expert_mlp2(xb, pp, w2_0, b2_0, w2_1, b2_1, w2_2, b2_2,
                        (size_t)h * 16 + c1, rr);
#pragma unroll
            for (int n = 0; n < 2; n++) {
                int q = pp[n];
                out[2 * NPIX + rowoff + q] = rr[n].ent;   // e2
                int raw = c1 * 12 + rr[n].idx - 2;
                sRaw[q] = raw;
                int cl = raw < 0 ? 0 : (raw > 191 ? 191 : raw);
                sCls[q] = cl;   // own pair's pixels only (dup writes same value)
            }
        }
    }
    __syncthreads();
    sCnt[t] = 0;
    if (t < 64) sCnt[128 + t] = 0;
    __syncthreads();

    // ---- counting sort by clipped inds12 (192 bins, even-aligned segments) ----
    rkA = atomicAdd(&sCnt[sCls[t]], 1);
    rkB = atomicAdd(&sCnt[sCls[t + 128]], 1);
    __syncthreads();
    {
        int lane = t & 63;
        if (t < 64) {
            int ce = (sCnt[lane] + 1) & ~1;
            int incl = ce;
#pragma unroll
            for (int d = 1; d < 64; d <<= 1) {
                int n = __shfl_up(incl, d, 64);
                if (lane >= d) incl += n;
            }
            sScan[lane] = incl;
            int ce2 = (sCnt[128 + lane] + 1) & ~1;
            int incl2 = ce2;
#pragma unroll
            for (int d = 1; d < 64; d <<= 1) {
                int n = __shfl_up(incl2, d, 64);
                if (lane >= d) incl2 += n;
            }
            sScan[128 + lane] = incl2;
        } else {
            int ce = (sCnt[64 + lane] + 1) & ~1;
            int incl = ce;
#pragma unroll
            for (int d = 1; d < 64; d <<= 1) {
                int n = __shfl_up(incl, d, 64);
                if (lane >= d) incl += n;
            }
            sScan[64 + lane] = incl;
        }
    }
    __syncthreads();
    {
        int ce = (sCnt[t] + 1) & ~1;
        sOffs[t] = sScan[t] - ce + (t >= 64 ? sScan[63] : 0);
        if (t < 64) {
            int b2 = 128 + t;
            int ce2 = (sCnt[b2] + 1) & ~1;
            sOffs[b2] = sScan[b2] - ce2 + sScan[63] + sScan[127];
        }
        if (t == 0) sTot = sScan[63] + sScan[127] + sScan[191];
    }
    __syncthreads();
    sPerm[sOffs[sCls[t]] + rkA] = t;
    sPerm[sOffs[sCls[t + 128]] + rkB] = t + 128;
    __syncthreads();
    {
        if (sCnt[t] & 1) { int g = sOffs[t] + sCnt[t]; sPerm[g] = sPerm[g - 1]; }
        if (t < 64) {
            int b2 = 128 + t;
            if (sCnt[b2] & 1) { int g = sOffs[b2] + sCnt[b2]; sPerm[g] = sPerm[g - 1]; }
        }
    }
    __syncthreads();

    // ---- stage 3: same-expert pairs ----
    {
        const int P = sTot >> 1;
        const float* xb = x_in + (size_t)64 * NPIX + rowoff;
        for (int j = t; j < P; j += 128) {
            int pp[2] = { sPerm[2 * j], sPerm[2 * j + 1] };
            int cl = sCls[pp[0]];
            Res rr[2];
            expert_mlp2(xb, pp, w3_0, b3_0, w3_1, b3_1, w3_2, b3_2,
                        (size_t)h * 192 + cl, rr);
#pragma unroll
            for (int n = 0; n < 2; n++) {
                int q = pp[n];
                int raw = sRaw[q];
                out[3 * NPIX + rowoff + q] = rr[n].ent;   // e3
                int i123 = raw * 8 + rr[n].idx - 4;
                i123 = i123 < 0 ? 0 : (i123 > 1535 ? 1535 : i123);
                out[rowoff + q] = (float)i123;            // inds123 as float
            }
        }
    }
}

extern "C" void kernel_launch(void* const* d_in, const int* in_sizes, int n_in,
                              void* d_out, int out_size, void* d_ws, size_t ws_size,
                              hipStream_t stream) {
    const float* P[19];
    for (int i = 0; i < 19 && i < n_in; i++) P[i] = (const float*)d_in[i];

    const float *x_in, *W1[3], *B1[3], *W2[3], *B2[3], *W3[3], *B3[3];
    x_in = P[0];
    bool dict_order = (in_sizes[2] == 448 * 32);
    if (dict_order) {
        W1[0] = P[1];  B1[0] = P[2];  W1[1] = P[3];  B1[1] = P[4];  W1[2] = P[5];  B1[2] = P[6];
        W2[0] = P[7];  B2[0] = P[8];  W2[1] = P[9];  B2[1] = P[10]; W2[2] = P[11]; B2[2] = P[12];
        W3[0] = P[13]; B3[0] = P[14]; W3[1] = P[15]; B3[1] = P[16]; W3[2] = P[17]; B3[2] = P[18];
    } else {
        W1[0] = P[1];  W1[1] = P[2];  W1[2] = P[3];  B1[0] = P[4];  B1[1] = P[5];  B1[2] = P[6];
        W2[0] = P[7];  W2[1] = P[8];  W2[2] = P[9];  B2[0] = P[10]; B2[1] = P[11]; B2[2] = P[12];
        W3[0] = P[13]; W3[1] = P[14]; W3[2] = P[15]; B3[0] = P[16]; B3[1] = P[17]; B3[2] = P[18];
    }

    float* out = (float*)d_out;
    hipLaunchKernelGGL(cls3_kernel, dim3(2 * HH), dim3(128), 0, stream,
                       x_in,
                       W1[0], B1[0], W1[1], B1[1], W1[2], B1[2],
                       W2[0], B2[0], W2[1], B2[1], W2[2], B2[2],
                       W3[0], B3[0], W3[1], B3[1], W3[2], B3[2],
                       out);
}

// Round 19
// 183.258 us; speedup vs baseline: 4.7698x; 1.0782x over previous
//
#include <hip/hip_runtime.h>

#define HH 448
#define WW 512
#define NPIX (HH * WW)

struct Res { int idx; float ent; };

__device__ __forceinline__ float lrelu(float v) { return v > 0.0f ? v : 0.01f * v; }

__device__ __forceinline__ Res argmax_ent16(const float* __restrict__ v) {
    float m = v[0]; int idx = 0;
#pragma unroll
    for (int i = 1; i < 16; i++) { if (v[i] > m) { m = v[i]; idx = i; } }
    float s = 0.0f, dot = 0.0f;
#pragma unroll
    for (int i = 0; i < 16; i++) {
        float t = __expf(v[i] - m);
        s += t;
        dot = fmaf(t, v[i], dot);
    }
    Res r; r.idx = idx; r.ent = m + __logf(s) - dot / s;
    return r;
}

// NPX pixels, weight layout [in=32][OUT] (stages 2/3). Per-pixel fma order identical
// to the 1-pixel version (bitwise-stable). One weight float4 feeds 4*NPX fmas.
template <int NPX, int OUT>
__device__ __forceinline__ void layer_ioN(const float* __restrict__ w,
                                          const float* __restrict__ b,
                                          const float* __restrict__ x,
                                          float* __restrict__ y) {
    float acc[NPX][OUT];
#pragma unroll
    for (int n = 0; n < NPX; n++)
#pragma unroll
        for (int o = 0; o < OUT; o++) acc[n][o] = b[o];
#pragma unroll
    for (int i = 0; i < 32; i++) {
        const float4* row = (const float4*)(w + i * OUT);
#pragma unroll
        for (int q = 0; q < OUT / 4; q++) {
            float4 wv = row[q];
#pragma unroll
            for (int n = 0; n < NPX; n++) {
                float xi = x[n * 32 + i];
                acc[n][4 * q + 0] = fmaf(xi, wv.x, acc[n][4 * q + 0]);
                acc[n][4 * q + 1] = fmaf(xi, wv.y, acc[n][4 * q + 1]);
                acc[n][4 * q + 2] = fmaf(xi, wv.z, acc[n][4 * q + 2]);
                acc[n][4 * q + 3] = fmaf(xi, wv.w, acc[n][4 * q + 3]);
            }
        }
    }
#pragma unroll
    for (int n = 0; n < NPX; n++)
#pragma unroll
        for (int o = 0; o < OUT; o++) y[n * 32 + o] = acc[n][o];
}

// NPX pixels, weight layout [OUT][in=32] (stage 1, per-line uniform weights).
template <int NPX, int OUT>
__device__ __forceinline__ void layer_oiN(const float* __restrict__ w,
                                          const float* __restrict__ b,
                                          const float* __restrict__ x,
                                          float* __restrict__ y) {
#pragma unroll
    for (int o = 0; o < OUT; o++) {
        const float4* row = (const float4*)(w + o * 32);
        float a[NPX];
#pragma unroll
        for (int n = 0; n < NPX; n++) a[n] = b[o];
#pragma unroll
        for (int q = 0; q < 8; q++) {
            float4 wv = row[q];
#pragma unroll
            for (int n = 0; n < NPX; n++) {
                a[n] = fmaf(wv.x, x[n * 32 + 4 * q + 0], a[n]);
                a[n] = fmaf(wv.y, x[n * 32 + 4 * q + 1], a[n]);
                a[n] = fmaf(wv.z, x[n * 32 + 4 * q + 2], a[n]);
                a[n] = fmaf(wv.w, x[n * 32 + 4 * q + 3], a[n]);
            }
        }
#pragma unroll
        for (int n = 0; n < NPX; n++) y[n * 32 + o] = a[n];
    }
}

// 2-pixel expert MLP 32->32->32->16, shared expert e (per-lane global weights).
__device__ __forceinline__ void expert_mlp2(const float* __restrict__ xb,
                                            const int* __restrict__ p,
                                            const float* __restrict__ w0, const float* __restrict__ b0,
                                            const float* __restrict__ w1, const float* __restrict__ b1,
                                            const float* __restrict__ w2, const float* __restrict__ b2,
                                            size_t e, Res* __restrict__ r) {
    float x[64], y[64];
#pragma unroll
    for (int n = 0; n < 2; n++)
#pragma unroll
        for (int c = 0; c < 32; c++) x[n * 32 + c] = xb[(size_t)c * NPIX + p[n]];
    layer_ioN<2, 32>(w0 + e * 1024, b0 + e * 32, x, y);
#pragma unroll
    for (int k = 0; k < 64; k++) y[k] = lrelu(y[k]);
    layer_ioN<2, 32>(w1 + e * 1024, b1 + e * 32, y, x);
#pragma unroll
    for (int k = 0; k < 64; k++) x[k] = lrelu(x[k]);
    layer_ioN<2, 16>(w2 + e * 512, b2 + e * 16, x, y);
    r[0] = argmax_ent16(y);
    r[1] = argmax_ent16(y + 32);
}

__global__ __launch_bounds__(256, 2) void cls3_kernel(
    const float* __restrict__ x_in,
    const float* __restrict__ w1_0, const float* __restrict__ b1_0,
    const float* __restrict__ w1_1, const float* __restrict__ b1_1,
    const float* __restrict__ w1_2, const float* __restrict__ b1_2,
    const float* __restrict__ w2_0, const float* __restrict__ b2_0,
    const float* __restrict__ w2_1, const float* __restrict__ b2_1,
    const float* __restrict__ w2_2, const float* __restrict__ b2_2,
    const float* __restrict__ w3_0, const float* __restrict__ b3_0,
    const float* __restrict__ w3_1, const float* __restrict__ b3_1,
    const float* __restrict__ w3_2, const float* __restrict__ b3_2,
    float* __restrict__ out) {
    __shared__ int sCls[512];
    __shared__ int sRaw[512];
    __shared__ int sPerm[768];   // even-aligned slots (<=704 used)
    __shared__ int sCnt[192];
    __shared__ int sScan[192];
    __shared__ int sOffs[192];
    __shared__ int sTot;

    const int h = blockIdx.x;            // one block = one full line
    const int t = threadIdx.x;           // 0..255
    const size_t rowoff = (size_t)h * WW;

    // ---- stage 1: 2 px/thread (t, t+256), per-line uniform weights ----
    {
        float x[64], y[64];
#pragma unroll
        for (int c = 0; c < 32; c++) {
            x[c]      = x_in[(size_t)c * NPIX + rowoff + t];
            x[32 + c] = x_in[(size_t)c * NPIX + rowoff + t + 256];
        }
        layer_oiN<2, 32>(w1_0 + (size_t)h * 1024, b1_0 + (size_t)h * 32, x, y);
#pragma unroll
        for (int k = 0; k < 64; k++) y[k] = lrelu(y[k]);
        layer_oiN<2, 32>(w1_1 + (size_t)h * 1024, b1_1 + (size_t)h * 32, y, x);
#pragma unroll
        for (int k = 0; k < 64; k++) x[k] = lrelu(x[k]);
        layer_oiN<2, 16>(w1_2 + (size_t)h * 512, b1_2 + (size_t)h * 16, x, y);
        Res r0 = argmax_ent16(y);
        Res r1 = argmax_ent16(y + 32);
        out[NPIX + rowoff + t] = r0.ent;          // e1
        out[NPIX + rowoff + t + 256] = r1.ent;
        sCls[t] = r0.idx;
        sCls[t + 256] = r1.idx;
    }
    if (t < 16) sCnt[t] = 0;
    __syncthreads();

    // ---- counting sort by inds1 (16 bins, 512 px, even-aligned segments) ----
    int rkA = atomicAdd(&sCnt[sCls[t]], 1);
    int rkB = atomicAdd(&sCnt[sCls[t + 256]], 1);
    __syncthreads();
    if (t < 16) {
        int ce = (sCnt[t] + 1) & ~1;
        int incl = ce;
#pragma unroll
        for (int d = 1; d < 16; d <<= 1) {
            int n = __shfl_up(incl, d, 64);
            if (t >= d) incl += n;
        }
        sOffs[t] = incl - ce;
        if (t == 15) sTot = incl;
    }
    __syncthreads();
    sPerm[sOffs[sCls[t]] + rkA] = t;
    sPerm[sOffs[sCls[t + 256]] + rkB] = t + 256;
    __syncthreads();
    if (t < 16 && (sCnt[t] & 1)) {   // duplicate last pixel of odd segments
        int g = sOffs[t] + sCnt[t];
        sPerm[g] = sPerm[g - 1];
    }
    __syncthreads();

    // ---- stage 2: same-expert pairs over the full line ----
    {
        const int P = sTot >> 1;
        const float* xb = x_in + (size_t)32 * NPIX + rowoff;
        for (int j = t; j < P; j += 256) {
            int pp[2] = { sPerm[2 * j], sPerm[2 * j + 1] };
            int c1 = sCls[pp[0]];
            Res rr[2];
            expert_mlp2(xb, pp, w2_0, b2_0, w2_1, b2_1, w2_2, b2_2,
                        (size_t)h * 16 + c1, rr);
#pragma unroll
            for (int n = 0; n < 2; n++) {
                int q = pp[n];
                out[2 * NPIX + rowoff + q] = rr[n].ent;   // e2
                int raw = c1 * 12 + rr[n].idx - 2;
                sRaw[q] = raw;
                int cl = raw < 0 ? 0 : (raw > 191 ? 191 : raw);
                sCls[q] = cl;   // own pair's pixels only (dup writes same value)
            }
        }
    }
    __syncthreads();
    if (t < 192) sCnt[t] = 0;
    __syncthreads();

    // ---- counting sort by clipped inds12 (192 bins, 512 px, even-aligned) ----
    rkA = atomicAdd(&sCnt[sCls[t]], 1);
    rkB = atomicAdd(&sCnt[sCls[t + 256]], 1);
    __syncthreads();
    if (t < 192) {                       // 3 waves scan their own 64-bin chunk
        int lane = t & 63;
        int ce = (sCnt[t] + 1) & ~1;
        int incl = ce;
#pragma unroll
        for (int d = 1; d < 64; d <<= 1) {
            int n = __shfl_up(incl, d, 64);
            if (lane >= d) incl += n;
        }
        sScan[t] = incl;
    }
    __syncthreads();
    if (t < 192) {
        int ce = (sCnt[t] + 1) & ~1;
        int add = 0;
        if (t >= 64) add += sScan[63];
        if (t >= 128) add += sScan[127];
        sOffs[t] = sScan[t] + add - ce;
    }
    if (t == 0) sTot = sScan[63] + sScan[127] + sScan[191];
    __syncthreads();
    sPerm[sOffs[sCls[t]] + rkA] = t;
    sPerm[sOffs[sCls[t + 256]] + rkB] = t + 256;
    __syncthreads();
    if (t < 192 && (sCnt[t] & 1)) {
        int g = sOffs[t] + sCnt[t];
        sPerm[g] = sPerm[g - 1];
    }
    __syncthreads();

    // ---- stage 3: same-expert pairs over the full line ----
    {
        const int P = sTot >> 1;
        const float* xb = x_in + (size_t)64 * NPIX + rowoff;
        for (int j = t; j < P; j += 256) {
            int pp[2] = { sPerm[2 * j], sPerm[2 * j + 1] };
            int cl = sCls[pp[0]];
            Res rr[2];
            expert_mlp2(xb, pp, w3_0, b3_0, w3_1, b3_1, w3_2, b3_2,
                        (size_t)h * 192 + cl, rr);
#pragma unroll
            for (int n = 0; n < 2; n++) {
                int q = pp[n];
                int raw = sRaw[q];
                out[3 * NPIX + rowoff + q] = rr[n].ent;   // e3
                int i123 = raw * 8 + rr[n].idx - 4;
                i123 = i123 < 0 ? 0 : (i123 > 1535 ? 1535 : i123);
                out[rowoff + q] = (float)i123;            // inds123 as float
            }
        }
    }
}

extern "C" void kernel_launch(void* const* d_in, const int* in_sizes, int n_in,
                              void* d_out, int out_size, void* d_ws, size_t ws_size,
                              hipStream_t stream) {
    const float* P[19];
    for (int i = 0; i < 19 && i < n_in; i++) P[i] = (const float*)d_in[i];

    const float *x_in, *W1[3], *B1[3], *W2[3], *B2[3], *W3[3], *B3[3];
    x_in = P[0];
    bool dict_order = (in_sizes[2] == 448 * 32);
    if (dict_order) {
        W1[0] = P[1];  B1[0] = P[2];  W1[1] = P[3];  B1[1] = P[4];  W1[2] = P[5];  B1[2] = P[6];
        W2[0] = P[7];  B2[0] = P[8];  W2[1] = P[9];  B2[1] = P[10]; W2[2] = P[11]; B2[2] = P[12];
        W3[0] = P[13]; B3[0] = P[14]; W3[1] = P[15]; B3[1] = P[16]; W3[2] = P[17]; B3[2] = P[18];
    } else {
        W1[0] = P[1];  W1[1] = P[2];  W1[2] = P[3];  B1[0] = P[4];  B1[1] = P[5];  B1[2] = P[6];
        W2[0] = P[7];  W2[1] = P[8];  W2[2] = P[9];  B2[0] = P[10]; B2[1] = P[11]; B2[2] = P[12];
        W3[0] = P[13]; W3[1] = P[14]; W3[2] = P[15]; B3[0] = P[16]; B3[1] = P[17]; B3[2] = P[18];
    }

    float* out = (float*)d_out;
    hipLaunchKernelGGL(cls3_kernel, dim3(HH), dim3(256), 0, stream,
                       x_in,
                       W1[0], B1[0], W1[1], B1[1], W1[2], B1[2],
                       W2[0], B2[0], W2[1], B2[1], W2[2], B2[2],
                       W3[0], B3[0], W3[1], B3[1], W3[2], B3[2],
                       out);
}

// Round 20
// 173.658 us; speedup vs baseline: 5.0335x; 1.0553x over previous
//
#include <hip/hip_runtime.h>

#define HH 448
#define WW 512
#define NPIX (HH * WW)

struct Res { int idx; float ent; };

__device__ __forceinline__ float lrelu(float v) { return v > 0.0f ? v : 0.01f * v; }

__device__ __forceinline__ Res argmax_ent16(const float* __restrict__ v) {
    float m = v[0]; int idx = 0;
#pragma unroll
    for (int i = 1; i < 16; i++) { if (v[i] > m) { m = v[i]; idx = i; } }
    float s = 0.0f, dot = 0.0f;
#pragma unroll
    for (int i = 0; i < 16; i++) {
        float t = __expf(v[i] - m);
        s += t;
        dot = fmaf(t, v[i], dot);
    }
    Res r; r.idx = idx; r.ent = m + __logf(s) - dot / s;
    return r;
}

// NPX pixels, weight layout [in=32][OUT] (stages 2/3). Per-pixel fma order identical
// to the 1-pixel version (bitwise-stable). One weight float4 feeds 4*NPX fmas.
template <int NPX, int OUT>
__device__ __forceinline__ void layer_ioN(const float* __restrict__ w,
                                          const float* __restrict__ b,
                                          const float* __restrict__ x,
                                          float* __restrict__ y) {
    float acc[NPX][OUT];
#pragma unroll
    for (int n = 0; n < NPX; n++)
#pragma unroll
        for (int o = 0; o < OUT; o++) acc[n][o] = b[o];
#pragma unroll
    for (int i = 0; i < 32; i++) {
        const float4* row = (const float4*)(w + i * OUT);
#pragma unroll
        for (int q = 0; q < OUT / 4; q++) {
            float4 wv = row[q];
#pragma unroll
            for (int n = 0; n < NPX; n++) {
                float xi = x[n * 32 + i];
                acc[n][4 * q + 0] = fmaf(xi, wv.x, acc[n][4 * q + 0]);
                acc[n][4 * q + 1] = fmaf(xi, wv.y, acc[n][4 * q + 1]);
                acc[n][4 * q + 2] = fmaf(xi, wv.z, acc[n][4 * q + 2]);
                acc[n][4 * q + 3] = fmaf(xi, wv.w, acc[n][4 * q + 3]);
            }
        }
    }
#pragma unroll
    for (int n = 0; n < NPX; n++)
#pragma unroll
        for (int o = 0; o < OUT; o++) y[n * 32 + o] = acc[n][o];
}

// NPX pixels, weight layout [OUT][in=32] (stage 1, per-line uniform weights).
template <int NPX, int OUT>
__device__ __forceinline__ void layer_oiN(const float* __restrict__ w,
                                          const float* __restrict__ b,
                                          const float* __restrict__ x,
                                          float* __restrict__ y) {
#pragma unroll
    for (int o = 0; o < OUT; o++) {
        const float4* row = (const float4*)(w + o * 32);
        float a[NPX];
#pragma unroll
        for (int n = 0; n < NPX; n++) a[n] = b[o];
#pragma unroll
        for (int q = 0; q < 8; q++) {
            float4 wv = row[q];
#pragma unroll
            for (int n = 0; n < NPX; n++) {
                a[n] = fmaf(wv.x, x[n * 32 + 4 * q + 0], a[n]);
                a[n] = fmaf(wv.y, x[n * 32 + 4 * q + 1], a[n]);
                a[n] = fmaf(wv.z, x[n * 32 + 4 * q + 2], a[n]);
                a[n] = fmaf(wv.w, x[n * 32 + 4 * q + 3], a[n]);
            }
        }
#pragma unroll
        for (int n = 0; n < NPX; n++) y[n * 32 + o] = a[n];
    }
}

// 2-pixel expert MLP 32->32->32->16, shared expert e; x comes from the LDS x-slab
// (layout [c][512]; bank = px mod 32 -> ~2-way across sorted lanes = free).
__device__ __forceinline__ void expert_mlp2(const float* __restrict__ sX,
                                            const int* __restrict__ p,
                                            const float* __restrict__ w0, const float* __restrict__ b0,
                                            const float* __restrict__ w1, const float* __restrict__ b1,
                                            const float* __restrict__ w2, const float* __restrict__ b2,
                                            size_t e, Res* __restrict__ r) {
    float x[64], y[64];
#pragma unroll
    for (int n = 0; n < 2; n++)
#pragma unroll
        for (int c = 0; c < 32; c++) x[n * 32 + c] = sX[c * 512 + p[n]];
    layer_ioN<2, 32>(w0 + e * 1024, b0 + e * 32, x, y);
#pragma unroll
    for (int k = 0; k < 64; k++) y[k] = lrelu(y[k]);
    layer_ioN<2, 32>(w1 + e * 1024, b1 + e * 32, y, x);
#pragma unroll
    for (int k = 0; k < 64; k++) x[k] = lrelu(x[k]);
    layer_ioN<2, 16>(w2 + e * 512, b2 + e * 16, x, y);
    r[0] = argmax_ent16(y);
    r[1] = argmax_ent16(y + 32);
}

__global__ __launch_bounds__(256, 2) void cls3_kernel(
    const float* __restrict__ x_in,
    const float* __restrict__ w1_0, const float* __restrict__ b1_0,
    const float* __restrict__ w1_1, const float* __restrict__ b1_1,
    const float* __restrict__ w1_2, const float* __restrict__ b1_2,
    const float* __restrict__ w2_0, const float* __restrict__ b2_0,
    const float* __restrict__ w2_1, const float* __restrict__ b2_1,
    const float* __restrict__ w2_2, const float* __restrict__ b2_2,
    const float* __restrict__ w3_0, const float* __restrict__ b3_0,
    const float* __restrict__ w3_1, const float* __restrict__ b3_1,
    const float* __restrict__ w3_2, const float* __restrict__ b3_2,
    float* __restrict__ out) {
    __shared__ float sX[32 * 512];   // 64 KB x-slab, layout [c][px]
    __shared__ int sCls[512];
    __shared__ int sRaw[512];
    __shared__ int sPerm[768];       // even-aligned slots (<=704 used)
    __shared__ int sCnt[192];
    __shared__ int sScan[192];
    __shared__ int sOffs[192];
    __shared__ int sTot;

    const int h = blockIdx.x;            // one block = one full line
    const int t = threadIdx.x;           // 0..255
    const size_t rowoff = (size_t)h * WW;

    // ---- stage 1: 2 px/thread (t, t+256), per-line uniform weights ----
    {
        float x[64], y[64];
#pragma unroll
        for (int c = 0; c < 32; c++) {
            x[c]      = x_in[(size_t)c * NPIX + rowoff + t];
            x[32 + c] = x_in[(size_t)c * NPIX + rowoff + t + 256];
        }
        layer_oiN<2, 32>(w1_0 + (size_t)h * 1024, b1_0 + (size_t)h * 32, x, y);
#pragma unroll
        for (int k = 0; k < 64; k++) y[k] = lrelu(y[k]);
        layer_oiN<2, 32>(w1_1 + (size_t)h * 1024, b1_1 + (size_t)h * 32, y, x);
#pragma unroll
        for (int k = 0; k < 64; k++) x[k] = lrelu(x[k]);
        layer_oiN<2, 16>(w1_2 + (size_t)h * 512, b1_2 + (size_t)h * 16, x, y);
        Res r0 = argmax_ent16(y);
        Res r1 = argmax_ent16(y + 32);
        out[NPIX + rowoff + t] = r0.ent;          // e1
        out[NPIX + rowoff + t + 256] = r1.ent;
        sCls[t] = r0.idx;
        sCls[t + 256] = r1.idx;
    }
    if (t < 16) sCnt[t] = 0;
    // stage x-slab for stage 2 (channels 32:64), coalesced float4, layout-preserving
    {
        const float* gx = x_in + (size_t)32 * NPIX + rowoff;
        for (int i = t; i < 32 * 128; i += 256) {
            int c = i >> 7, g4 = (i & 127) << 2;
            *(float4*)(&sX[c * 512 + g4]) =
                *(const float4*)(gx + (size_t)c * NPIX + g4);
        }
    }
    __syncthreads();

    // ---- counting sort by inds1 (16 bins, 512 px, even-aligned segments) ----
    int rkA = atomicAdd(&sCnt[sCls[t]], 1);
    int rkB = atomicAdd(&sCnt[sCls[t + 256]], 1);
    __syncthreads();
    if (t < 16) {
        int ce = (sCnt[t] + 1) & ~1;
        int incl = ce;
#pragma unroll
        for (int d = 1; d < 16; d <<= 1) {
            int n = __shfl_up(incl, d, 64);
            if (t >= d) incl += n;
        }
        sOffs[t] = incl - ce;
        if (t == 15) sTot = incl;
    }
    __syncthreads();
    sPerm[sOffs[sCls[t]] + rkA] = t;
    sPerm[sOffs[sCls[t + 256]] + rkB] = t + 256;
    __syncthreads();
    if (t < 16 && (sCnt[t] & 1)) {   // duplicate last pixel of odd segments
        int g = sOffs[t] + sCnt[t];
        sPerm[g] = sPerm[g - 1];
    }
    __syncthreads();

    // ---- stage 2: same-expert pairs over the full line, x from LDS ----
    {
        const int P = sTot >> 1;
        for (int j = t; j < P; j += 256) {
            int pp[2] = { sPerm[2 * j], sPerm[2 * j + 1] };
            int c1 = sCls[pp[0]];
            Res rr[2];
            expert_mlp2(sX, pp, w2_0, b2_0, w2_1, b2_1, w2_2, b2_2,
                        (size_t)h * 16 + c1, rr);
#pragma unroll
            for (int n = 0; n < 2; n++) {
                int q = pp[n];
                out[2 * NPIX + rowoff + q] = rr[n].ent;   // e2
                int raw = c1 * 12 + rr[n].idx - 2;
                sRaw[q] = raw;
                int cl = raw < 0 ? 0 : (raw > 191 ? 191 : raw);
                sCls[q] = cl;   // own pair's pixels only (dup writes same value)
            }
        }
    }
    __syncthreads();
    if (t < 192) sCnt[t] = 0;
    // restage x-slab for stage 3 (channels 64:96)
    {
        const float* gx = x_in + (size_t)64 * NPIX + rowoff;
        for (int i = t; i < 32 * 128; i += 256) {
            int c = i >> 7, g4 = (i & 127) << 2;
            *(float4*)(&sX[c * 512 + g4]) =
                *(const float4*)(gx + (size_t)c * NPIX + g4);
        }
    }
    __syncthreads();

    // ---- counting sort by clipped inds12 (192 bins, 512 px, even-aligned) ----
    rkA = atomicAdd(&sCnt[sCls[t]], 1);
    rkB = atomicAdd(&sCnt[sCls[t + 256]], 1);
    __syncthreads();
    if (t < 192) {                       // 3 waves scan their own 64-bin chunk
        int lane = t & 63;
        int ce = (sCnt[t] + 1) & ~1;
        int incl = ce;
#pragma unroll
        for (int d = 1; d < 64; d <<= 1) {
            int n = __shfl_up(incl, d, 64);
            if (lane >= d) incl += n;
        }
        sScan[t] = incl;
    }
    __syncthreads();
    if (t < 192) {
        int ce = (sCnt[t] + 1) & ~1;
        int add = 0;
        if (t >= 64) add += sScan[63];
        if (t >= 128) add += sScan[127];
        sOffs[t] = sScan[t] + add - ce;
    }
    if (t == 0) sTot = sScan[63] + sScan[127] + sScan[191];
    __syncthreads();
    sPerm[sOffs[sCls[t]] + rkA] = t;
    sPerm[sOffs[sCls[t + 256]] + rkB] = t + 256;
    __syncthreads();
    if (t < 192 && (sCnt[t] & 1)) {
        int g = sOffs[t] + sCnt[t];
        sPerm[g] = sPerm[g - 1];
    }
    __syncthreads();

    // ---- stage 3: same-expert pairs over the full line, x from LDS ----
    {
        const int P = sTot >> 1;
        for (int j = t; j < P; j += 256) {
            int pp[2] = { sPerm[2 * j], sPerm[2 * j + 1] };
            int cl = sCls[pp[0]];
            Res rr[2];
            expert_mlp2(sX, pp, w3_0, b3_0, w3_1, b3_1, w3_2, b3_2,
                        (size_t)h * 192 + cl, rr);
#pragma unroll
            for (int n = 0; n < 2; n++) {
                int q = pp[n];
                int raw = sRaw[q];
                out[3 * NPIX + rowoff + q] = rr[n].ent;   // e3
                int i123 = raw * 8 + rr[n].idx - 4;
                i123 = i123 < 0 ? 0 : (i123 > 1535 ? 1535 : i123);
                out[rowoff + q] = (float)i123;            // inds123 as float
            }
        }
    }
}

extern "C" void kernel_launch(void* const* d_in, const int* in_sizes, int n_in,
                              void* d_out, int out_size, void* d_ws, size_t ws_size,
                              hipStream_t stream) {
    const float* P[19];
    for (int i = 0; i < 19 && i < n_in; i++) P[i] = (const float*)d_in[i];

    const float *x_in, *W1[3], *B1[3], *W2[3], *B2[3], *W3[3], *B3[3];
    x_in = P[0];
    bool dict_order = (in_sizes[2] == 448 * 32);
    if (dict_order) {
        W1[0] = P[1];  B1[0] = P[2];  W1[1] = P[3];  B1[1] = P[4];  W1[2] = P[5];  B1[2] = P[6];
        W2[0] = P[7];  B2[0] = P[8];  W2[1] = P[9];  B2[1] = P[10]; W2[2] = P[11]; B2[2] = P[12];
        W3[0] = P[13]; B3[0] = P[14]; W3[1] = P[15]; B3[1] = P[16]; W3[2] = P[17]; B3[2] = P[18];
    } else {
        W1[0] = P[1];  W1[1] = P[2];  W1[2] = P[3];  B1[0] = P[4];  B1[1] = P[5];  B1[2] = P[6];
        W2[0] = P[7];  W2[1] = P[8];  W2[2] = P[9];  B2[0] = P[10]; B2[1] = P[11]; B2[2] = P[12];
        W3[0] = P[13]; W3[1] = P[14]; W3[2] = P[15]; B3[0] = P[16]; B3[1] = P[17]; B3[2] = P[18];
    }

    float* out = (float*)d_out;
    hipLaunchKernelGGL(cls3_kernel, dim3(HH), dim3(256), 0, stream,
                       x_in,
                       W1[0], B1[0], W1[1], B1[1], W1[2], B1[2],
                       W2[0], B2[0], W2[1], B2[1], W2[2], B2[2],
                       W3[0], B3[0], W3[1], B3[1], W3[2], B3[2],
                       out);
}